// Round 10
// baseline (433.585 us; speedup 1.0000x reference)
//
#include <hip/hip_runtime.h>

#define NB 64
#define ND 128
#define NT 2048
#define NK 1024
#define NN (NB*NT)            // 131072
#define DTSTRIDE (ND*NT)      // 262144, b-stride in x

typedef __attribute__((ext_vector_type(8))) short bf16x8;
typedef __attribute__((ext_vector_type(4))) float floatx4;

// ---- workspace layout (float index) ----
#define WS_ET    0            // 131072 floats, ET[d][k] fp32 (for out-tail gather)
#define WS_SSX   131072       // (unused since R10 — ssx is gemm-internal)
#define WS_SSE   262144       // 1024 floats,  |e_k|^2
#define WS_DW    263168       // (unused, kept for layout)
#define WS_CS    394240       // 1024 floats
#define WS_CNT   395264       // 1024 ints, counts
#define WS_IDX   396288       // 131072 ints, argmin indices
#define WS_LOSS  527360       // 1 float
#define WS_OFFS  527364       // 1024 ints
#define WS_CUR   528388       // 1024 ints
#define WS_LIST  529412       // 131072 ints
#define WS_XT    660736       // 16777216 floats, xt[n][d] (written by gemm now)
#define WS_EB    17437952     // 3 x 131072 ushorts: bf16 e-planes, PRE-SWIZZLED
                              // [dchunk 4][k 1024][slot 4][8] ; slot = q ^ ((k>>1)&3)

// ---- output layout ----
#define O_OUT 0
#define O_LC  16777216
#define O_LV  16777217
#define O_IDX 16777218
#define O_NE  16908290

#define GLL16(g, l) __builtin_amdgcn_global_load_lds( \
    (const __attribute__((address_space(1))) unsigned int*)(g), \
    (__attribute__((address_space(3))) unsigned int*)(l), 16, 0, 0)

// exact truncation split of fp32 into 3 bf16 (bit patterns) — R0 verified
__device__ inline void split1(float v, unsigned short &a, unsigned short &b,
                              unsigned short &c) {
    unsigned int u = __float_as_uint(v);
    a = (unsigned short)(u >> 16);
    float f1 = __uint_as_float(u & 0xffff0000u);
    float r = v - f1;
    unsigned int ur = __float_as_uint(r);
    b = (unsigned short)(ur >> 16);
    float f2 = __uint_as_float(ur & 0xffff0000u);
    float r2 = r - f2;
    c = (unsigned short)(__float_as_uint(r2) >> 16);
}

// pack 2 consecutive elements into one uint per plane
__device__ inline void split2(float va, float vb, unsigned int &p1,
                              unsigned int &p2, unsigned int &p3) {
    unsigned int ua = __float_as_uint(va), ub = __float_as_uint(vb);
    p1 = (ua >> 16) | (ub & 0xffff0000u);
    float fa = __uint_as_float(ua & 0xffff0000u);
    float fb = __uint_as_float(ub & 0xffff0000u);
    float ra = va - fa, rb = vb - fb;
    unsigned int ura = __float_as_uint(ra), urb = __float_as_uint(rb);
    p2 = (ura >> 16) | (urb & 0xffff0000u);
    float f2a = __uint_as_float(ura & 0xffff0000u);
    float f2b = __uint_as_float(urb & 0xffff0000u);
    float r2a = ra - f2a, r2b = rb - f2b;
    p3 = (__float_as_uint(r2a) >> 16) | (__float_as_uint(r2b) & 0xffff0000u);
}

// Kernel 1: ET fp32 [d][k], sse, bf16 e-planes pre-swizzled (R4 verified).
__global__ void prep_e(const float* __restrict__ emb, float* __restrict__ ET,
                       float* __restrict__ sse, unsigned short* __restrict__ eb1,
                       unsigned short* __restrict__ eb2, unsigned short* __restrict__ eb3) {
    int tid = threadIdx.x;
    int k   = blockIdx.x * 16 + (tid >> 4);
    int l   = tid & 15;
    float ss = 0.f;
    #pragma unroll
    for (int it = 0; it < 2; ++it) {
        int d0 = l * 4 + it * 64;
        float4 v = *(const float4*)(emb + k * ND + d0);
        ET[(d0+0)*NK + k] = v.x;
        ET[(d0+1)*NK + k] = v.y;
        ET[(d0+2)*NK + k] = v.z;
        ET[(d0+3)*NK + k] = v.w;
        ss = fmaf(v.x, v.x, ss); ss = fmaf(v.y, v.y, ss);
        ss = fmaf(v.z, v.z, ss); ss = fmaf(v.w, v.w, ss);
        int dc  = (l >> 3) + it * 2;
        int d5  = d0 & 31;                 // 0,4,...,28
        int qb  = (d5 >> 3) & 3;           // 16B block index
        int sl  = qb ^ ((k >> 1) & 3);     // swizzled slot (matches LDS read)
        int off = (dc * NK + k) * 32 + (sl << 3) + (d5 & 7);
        ushort4 a, b, c;
        split1(v.x, a.x, b.x, c.x);
        split1(v.y, a.y, b.y, c.y);
        split1(v.z, a.z, b.z, c.z);
        split1(v.w, a.w, b.w, c.w);
        *(ushort4*)(eb1 + off) = a;
        *(ushort4*)(eb2 + off) = b;
        *(ushort4*)(eb3 + off) = c;
    }
    for (int m = 1; m <= 8; m <<= 1) ss += __shfl_xor(ss, m);
    if (l == 0) sse[k] = ss;
}

// stage the (ktp,dcp) e-slice into LDS buffer `bufidx` (async, 6 loads/wave).
__device__ __forceinline__ void stage_eb(int ktp, int dcp, int bufidx, int w, int lane,
        unsigned short* smem, const unsigned short* eb1,
        const unsigned short* eb2, const unsigned short* eb3) {
    int goff = (dcp << 15) + (ktp << 12);   // dc*32768 + kt*4096 ushorts
    int bufo = bufidx * 12288;
    #pragma unroll
    for (int i = 0; i < 2; ++i) {
        int ch = (w << 1) + i;                          // 1KB chunk 0..7
        int so = goff + (ch << 9) + (lane << 3);        // per-lane 16B
        GLL16(eb1 + so, &smem[bufo + 0*4096 + (ch << 9)]);
        GLL16(eb2 + so, &smem[bufo + 1*4096 + (ch << 9)]);
        GLL16(eb3 + so, &smem[bufo + 2*4096 + (ch << 9)]);
    }
}

__device__ __forceinline__ int m3(int v) { return v >= 3 ? v - 3 : v; }

// Kernel 3: MFMA distance GEMM (R8 counted-vmcnt triple-buffer, R9 fused
// out-tail) — R10: transpose_x DELETED, A-TILE TRANSPOSE FUSED IN.
// Prologue: block loads x[b][:][t0..t0+127] (64KB) in 4 dc-chunks of 32x128
// into LDS (buffer-2 area — dead until the first in-loop stage, which only
// targets buffer 2 AFTER the first in-loop barrier), then per chunk:
//  (a) extracts A fragments (same floats as old xt reads -> bit-identical
//      split2 fragments), (b) writes xt rows (by-product, for dw_sum),
//  (c) accumulates per-row |x|^2 with ONE THREAD PER ROW in the exact
//      ascending-d sequential fmaf chain of old calc_ssx -> bit-identical
//      ssx (tie-critical, R2/R3 lesson). ssx never touches global memory.
// vmcnt invariant at loop entry: queue = [xt-stores..., stage0, stage1];
// vmcnt(6) forces everything older than stage1 done => stage0 landed.
// Numerics bit-identical to R9 throughout.
// Precision note (R1-R3): 6-product bf16 3-plane set is the numerics floor.
// Occupancy notes: (256,2) is the HW truth (R7 spill disaster at (256,3));
// L2-direct B regressed (R5); 16-row waves double LDS traffic (R6).
__launch_bounds__(256, 2)
__global__ void gemm_argmin_mfma(float* __restrict__ xt,
                                 const unsigned short* __restrict__ eb1,
                                 const unsigned short* __restrict__ eb2,
                                 const unsigned short* __restrict__ eb3,
                                 const float* __restrict__ sse,
                                 const float* __restrict__ x, const float* __restrict__ ET,
                                 float* __restrict__ out, int* __restrict__ idxi,
                                 int* __restrict__ counts, float* __restrict__ loss) {
    __shared__ unsigned short smem[38912];   // 3 bufs x 12288 + sse 2048 = 76 KB
    int tid = threadIdx.x;
    int b   = blockIdx.x >> 4;
    int t0  = (blockIdx.x & 15) << 7;
    int n0  = b * NT + t0;

    int lane = tid & 63;
    int w    = tid >> 6;          // wave id: rows [w*32, w*32+32)
    int c    = lane & 15;
    int q    = lane >> 4;
    int slot = q ^ ((c >> 1) & 3);

    // LDS aliases in the buffer-2 region (dead before first in-loop stage)
    float* ax   = (float*)(smem + 24576);   // [32][129] fp32 chunk
    float* ssxr = (float*)(smem + 32832);   // [128] per-row |x|^2
    float* ssef = (float*)(smem + 36864);   // [1024] sse

    // hold sse in regs; LDS-write after the transpose (area is disjoint anyway)
    float4 ssetmp = ((const float4*)sse)[tid];

    // ---- fused A-tile transpose + xt write + exact ssx ----
    const float* xbase = x + (size_t)b * DTSTRIDE + t0;
    bf16x8 af[4][2][3];
    float ssacc = 0.f;                      // row (tid<128) running |x|^2
    #pragma unroll
    for (int dc = 0; dc < 4; ++dc) {
        float4 cv[4];
        #pragma unroll
        for (int rep = 0; rep < 4; ++rep) {
            int d  = rep * 8 + (tid >> 5);
            int t4 = (tid & 31) * 4;
            cv[rep] = *(const float4*)(xbase + (size_t)(dc*32 + d) * NT + t4);
        }
        __syncthreads();                    // prior chunk fully consumed
        #pragma unroll
        for (int rep = 0; rep < 4; ++rep) {
            int d  = rep * 8 + (tid >> 5);
            int t4 = (tid & 31) * 4;
            *(float4*)(ax + d * 129 + t4) = cv[rep];
        }
        __syncthreads();
        // (a) A fragments for this dc (same floats as old xt-row reads)
        #pragma unroll
        for (int i = 0; i < 2; ++i) {
            int r = w*32 + i*16 + c;
            float v[8];
            #pragma unroll
            for (int j = 0; j < 8; ++j) v[j] = ax[(q*8 + j) * 129 + r];
            unsigned int p1[4], p2[4], p3[4];
            split2(v[0], v[1], p1[0], p2[0], p3[0]);
            split2(v[2], v[3], p1[1], p2[1], p3[1]);
            split2(v[4], v[5], p1[2], p2[2], p3[2]);
            split2(v[6], v[7], p1[3], p2[3], p3[3]);
            uint4 u;
            u = make_uint4(p1[0], p1[1], p1[2], p1[3]); af[dc][i][0] = *(bf16x8*)&u;
            u = make_uint4(p2[0], p2[1], p2[2], p2[3]); af[dc][i][1] = *(bf16x8*)&u;
            u = make_uint4(p3[0], p3[1], p3[2], p3[3]); af[dc][i][2] = *(bf16x8*)&u;
        }
        // (c) per-row |x|^2: one thread per row, ascending-d chain (bit-exact)
        if (tid < 128) {
            #pragma unroll 8
            for (int d5 = 0; d5 < 32; ++d5) {
                float v = ax[d5 * 129 + tid];
                ssacc = fmaf(v, v, ssacc);
            }
        }
        // (b) xt rows (by-product for dw_sum), coalesced-ish float4
        {
            int tl = tid & 127, dh = tid >> 7;
            #pragma unroll
            for (int rep = 0; rep < 4; ++rep) {
                int d = dh * 16 + rep * 4;
                float4 vv;
                vv.x = ax[(d+0)*129 + tl]; vv.y = ax[(d+1)*129 + tl];
                vv.z = ax[(d+2)*129 + tl]; vv.w = ax[(d+3)*129 + tl];
                *(float4*)(xt + (size_t)(n0 + tl) * ND + dc*32 + d) = vv;
            }
        }
    }
    if (tid < 128) ssxr[tid] = ssacc;
    ((float4*)ssef)[tid] = ssetmp;
    __syncthreads();

    float ssxv[8];
    #pragma unroll
    for (int i = 0; i < 2; ++i)
        #pragma unroll
        for (int rr = 0; rr < 4; ++rr)
            ssxv[i*4+rr] = ssxr[w*32 + i*16 + q*4 + rr];

    // prologue staging: buffers 0 and 1 (12 VMEM ops, newest in queue)
    stage_eb(0, 0, 0, w, lane, smem, eb1, eb2, eb3);
    stage_eb(0, 1, 1, w, lane, smem, eb1, eb2, eb3);

    float bestD[8]; int bestK[8];
    #pragma unroll
    for (int i = 0; i < 8; ++i) { bestD[i] = 3.4e38f; bestK[i] = 0; }

    floatx4 acc[2][8];
    int b3 = 0;                    // kt % 3

    for (int kt = 0; kt < 8; ++kt) {
        #pragma unroll
        for (int i = 0; i < 2; ++i)
            #pragma unroll
            for (int j = 0; j < 8; ++j)
                acc[i][j] = (floatx4){0.f, 0.f, 0.f, 0.f};

        #pragma unroll
        for (int dc = 0; dc < 4; ++dc) {
            // compute buffer = it % 3, it = kt*4 + dc  (4 == 1 mod 3)
            int cur = (dc == 0 || dc == 3) ? b3 : m3(b3 + dc);

            // barrier(it): vmcnt(6) proves stage(it) landed (newest 6 =
            // stage(it+1)); final iteration drains fully.
            if (kt == 7 && dc == 3) {
                asm volatile("s_waitcnt vmcnt(0) lgkmcnt(0)" ::: "memory");
            } else {
                asm volatile("s_waitcnt vmcnt(6) lgkmcnt(0)" ::: "memory");
            }
            __builtin_amdgcn_s_barrier();

            // issue stage(it+2) into buffer (it+2)%3 — safe: all waves are
            // past the barrier ending compute on that buffer.
            if (dc == 0) {
                stage_eb(kt, 2, m3(b3 + 2), w, lane, smem, eb1, eb2, eb3);
            } else if (dc == 1) {
                stage_eb(kt, 3, b3, w, lane, smem, eb1, eb2, eb3);
            } else if (dc == 2) {
                if (kt < 7) stage_eb(kt + 1, 0, m3(b3 + 1), w, lane, smem, eb1, eb2, eb3);
            } else {
                if (kt < 7) stage_eb(kt + 1, 1, m3(b3 + 2), w, lane, smem, eb1, eb2, eb3);
            }

            int bufo = cur * 12288;
            __builtin_amdgcn_s_setprio(1);
            #pragma unroll
            for (int j = 0; j < 8; ++j) {
                int ro = bufo + ((j << 4) + c) * 32 + slot * 8;
                bf16x8 b1 = *(const bf16x8*)(&smem[ro + 0*4096]);
                bf16x8 b2 = *(const bf16x8*)(&smem[ro + 1*4096]);
                bf16x8 b3f = *(const bf16x8*)(&smem[ro + 2*4096]);
                #pragma unroll
                for (int i = 0; i < 2; ++i) {
                    acc[i][j] = __builtin_amdgcn_mfma_f32_16x16x32_bf16(af[dc][i][0], b1, acc[i][j], 0, 0, 0);
                    acc[i][j] = __builtin_amdgcn_mfma_f32_16x16x32_bf16(af[dc][i][0], b2, acc[i][j], 0, 0, 0);
                    acc[i][j] = __builtin_amdgcn_mfma_f32_16x16x32_bf16(af[dc][i][1], b1, acc[i][j], 0, 0, 0);
                    acc[i][j] = __builtin_amdgcn_mfma_f32_16x16x32_bf16(af[dc][i][1], b2, acc[i][j], 0, 0, 0);
                    acc[i][j] = __builtin_amdgcn_mfma_f32_16x16x32_bf16(af[dc][i][0], b3f, acc[i][j], 0, 0, 0);
                    acc[i][j] = __builtin_amdgcn_mfma_f32_16x16x32_bf16(af[dc][i][2], b1, acc[i][j], 0, 0, 0);
                }
            }
            __builtin_amdgcn_s_setprio(0);
        }

        // epilogue for kt (identical numerics to R0/R4; sse from LDS)
        #pragma unroll
        for (int j = 0; j < 8; ++j) {
            int   kidx = (kt << 7) + (j << 4) + c;
            float se = ssef[(kt << 7) + (j << 4) + c];
            #pragma unroll
            for (int i = 0; i < 2; ++i) {
                #pragma unroll
                for (int rr = 0; rr < 4; ++rr) {
                    float t1   = ssxv[i*4+rr] + se;
                    float dist = fmaf(-2.f, acc[i][j][rr], t1);
                    if (dist < bestD[i*4+rr]) { bestD[i*4+rr] = dist; bestK[i*4+rr] = kidx; }
                }
            }
        }
        b3 = m3(b3 + 1);
    }

    // cross-lane argmin over the 16 c-lanes (ties -> smaller k)
    #pragma unroll
    for (int i = 0; i < 8; ++i) {
        float d = bestD[i]; int kk = bestK[i];
        for (int m = 1; m <= 8; m <<= 1) {
            float od = __shfl_xor(d, m);
            int   ok = __shfl_xor(kk, m);
            if (od < d || (od == d && ok < kk)) { d = od; kk = ok; }
        }
        bestD[i] = d; bestK[i] = kk;
    }
    // per-row k -> LDS buffer 0 (dead after the final barrier)
    int* ksh = (int*)smem;
    if (c == 0) {
        float ls = 0.f;
        #pragma unroll
        for (int i = 0; i < 2; ++i)
            #pragma unroll
            for (int rr = 0; rr < 4; ++rr) {
                int r  = w*32 + i*16 + q*4 + rr;
                int n  = n0 + r;
                int kk = bestK[i*4+rr];
                out[O_IDX + n] = (float)kk;
                idxi[n] = kk;
                ksh[r] = kk;
                atomicAdd(&counts[kk], 1);
                ls += bestD[i*4+rr];
            }
        atomicAdd(loss, ls);
    }
    __syncthreads();

    // ---- fused straight-through output (old out_write, bit-identical) ----
    int tl2 = tid & 127;               // t within tile
    int dh  = tid >> 7;                // 0/1: d parity
    int kk2 = ksh[tl2];
    const float* xp2 = x + b * DTSTRIDE + t0 + tl2;
    float*       op2 = out + O_OUT + b * DTSTRIDE + t0 + tl2;
    #pragma unroll 4
    for (int s = 0; s < 64; ++s) {
        int d = s * 2 + dh;
        float xv = xp2[d * NT];
        float qv = ET[d * NK + kk2];
        op2[d * NT] = xv + (qv - xv);
    }
}

// Kernel 5: exclusive scan of counts + cluster-size/losses (merged, R6 verified).
__global__ void scan_cs(const int* __restrict__ counts, int* __restrict__ offs,
                        int* __restrict__ cur, const float* __restrict__ ch,
                        const float* __restrict__ loss, float* __restrict__ csv,
                        float* __restrict__ out) {
    __shared__ int   s[256];
    __shared__ float red[256];
    int tid = threadIdx.x;
    int c[4]; int sum = 0;
    #pragma unroll
    for (int j = 0; j < 4; ++j) { c[j] = counts[tid*4+j]; sum += c[j]; }
    s[tid] = sum; __syncthreads();
    for (int off = 1; off < 256; off <<= 1) {
        int v = (tid >= off) ? s[tid - off] : 0;
        __syncthreads();
        s[tid] += v;
        __syncthreads();
    }
    int base = (tid == 0) ? 0 : s[tid-1];
    #pragma unroll
    for (int j = 0; j < 4; ++j) {
        offs[tid*4+j] = base; cur[tid*4+j] = base; base += c[j];
    }
    __syncthreads();
    const float DECF = (float)(1.0 - 0.99);
    float sf = 0.f;
    #pragma unroll
    for (int rr = 0; rr < 4; ++rr) {
        int k = tid + rr * 256;
        float cc = (float)counts[k];
        float e = ch[k];
        float hid = e - (e - cc) * DECF;
        sf += hid / DECF;
    }
    red[tid] = sf; __syncthreads();
    for (int off = 128; off > 0; off >>= 1) {
        if (tid < off) red[tid] += red[tid + off];
        __syncthreads();
    }
    float n = red[0];
    const float KEPSF = (float)(1024.0 * 1e-5);
    #pragma unroll
    for (int rr = 0; rr < 4; ++rr) {
        int k = tid + rr * 256;
        float cc = (float)counts[k];
        float e = ch[k];
        float hid = e - (e - cc) * DECF;
        float a = hid / DECF;
        csv[k] = (a + 1e-5f) / (n + KEPSF) * n;
    }
    if (tid == 0) {
        float mean = loss[0] / 16777216.f;
        out[O_LC] = 0.25f * mean;
        out[O_LV] = mean;
    }
}

// Kernel 6: bucket row-ids by k (unchanged).
__global__ void fill_list(const int* __restrict__ idxi, int* __restrict__ cur,
                          int* __restrict__ list) {
    int n = blockIdx.x * 256 + threadIdx.x;
    int k = idxi[n];
    int pos = atomicAdd(&cur[k], 1);
    list[pos] = n;
}

// Kernel 7: dw[k][d] via bucketed gather from xt, with new_embeddings fused
// (R9 verified).
__global__ void dw_sum(const float* __restrict__ xt,
                       const int* __restrict__ counts, const int* __restrict__ offs,
                       const int* __restrict__ list, const float* __restrict__ dwh,
                       const float* __restrict__ csv, float* __restrict__ out) {
    __shared__ float red[128];
    int k = blockIdx.x;
    int d = threadIdx.x & 127;
    int h = threadIdx.x >> 7;
    int cnt = counts[k], base = offs[k];
    float acc = 0.f;
    for (int m = h; m < cnt; m += 2) {
        int n = list[base + m];
        acc += xt[(size_t)n * ND + d];
    }
    if (h == 1) red[d] = acc;
    __syncthreads();
    if (h == 0) {
        const float DECF = (float)(1.0 - 0.99);
        float dwv = acc + red[d];
        int   kd  = k * ND + d;
        float e   = dwh[kd];
        float hid = e - (e - dwv) * DECF;
        float a   = hid / DECF;
        out[O_NE + kd] = a / csv[k];
    }
}

extern "C" void kernel_launch(void* const* d_in, const int* in_sizes, int n_in,
                              void* d_out, int out_size, void* d_ws, size_t ws_size,
                              hipStream_t stream) {
    const float* x   = (const float*)d_in[0];
    const float* emb = (const float*)d_in[1];
    const float* dwh = (const float*)d_in[2];
    const float* ch  = (const float*)d_in[3];
    float* out = (float*)d_out;
    float* ws  = (float*)d_ws;

    float* ET   = ws + WS_ET;
    float* sse  = ws + WS_SSE;
    float* csv  = ws + WS_CS;
    int*   counts = (int*)(ws + WS_CNT);
    int*   idxi   = (int*)(ws + WS_IDX);
    float* loss   = ws + WS_LOSS;
    int*   offs   = (int*)(ws + WS_OFFS);
    int*   cur    = (int*)(ws + WS_CUR);
    int*   list   = (int*)(ws + WS_LIST);
    float* xt     = ws + WS_XT;
    unsigned short* eb1 = (unsigned short*)(ws + WS_EB);
    unsigned short* eb2 = eb1 + NK * ND;
    unsigned short* eb3 = eb2 + NK * ND;

    hipMemsetAsync(counts, 0, NK * sizeof(int), stream);
    hipMemsetAsync(loss, 0, sizeof(float), stream);

    prep_e         <<<64,   256, 0, stream>>>(emb, ET, sse, eb1, eb2, eb3);
    gemm_argmin_mfma<<<1024,256, 0, stream>>>(xt, eb1, eb2, eb3, sse, x, ET,
                                              out, idxi, counts, loss);
    scan_cs        <<<1,    256, 0, stream>>>(counts, offs, cur, ch, loss, csv, out);
    fill_list      <<<512,  256, 0, stream>>>(idxi, cur, list);
    dw_sum         <<<1024, 256, 0, stream>>>(xt, counts, offs, list, dwh, csv, out);
}

// Round 12
// 395.882 us; speedup vs baseline: 1.0952x; 1.0952x over previous
//
#include <hip/hip_runtime.h>

#define NB 64
#define ND 128
#define NT 2048
#define NK 1024
#define NN (NB*NT)            // 131072
#define DTSTRIDE (ND*NT)      // 262144, b-stride in x

typedef __attribute__((ext_vector_type(8))) short bf16x8;
typedef __attribute__((ext_vector_type(4))) float floatx4;

// ---- workspace layout (float index) ----
#define WS_ET    0            // 131072 floats, ET[d][k] fp32 (for out-tail gather)
#define WS_SSX   131072       // 131072 floats, |x_n|^2
#define WS_SSE   262144       // 1024 floats,  |e_k|^2
#define WS_DW    263168       // (unused, kept for layout)
#define WS_CS    394240       // 1024 floats
#define WS_CNT   395264       // 1024 ints, counts
#define WS_IDX   396288       // 131072 ints, argmin indices
#define WS_LOSS  527360       // 1 float
#define WS_OFFS  527364       // 1024 ints
#define WS_CUR   528388       // 1024 ints
#define WS_LIST  529412       // 131072 ints
#define WS_XT    660736       // 16777216 floats, xt[n][d]
#define WS_EB    17437952     // 3 x 131072 ushorts: bf16 e-planes, PRE-SWIZZLED
                              // [dchunk 4][k 1024][slot 4][8] ; slot = q ^ ((k>>1)&3)

// ---- output layout ----
#define O_OUT 0
#define O_LC  16777216
#define O_LV  16777217
#define O_IDX 16777218
#define O_NE  16908290

#define GLL16(g, l) __builtin_amdgcn_global_load_lds( \
    (const __attribute__((address_space(1))) unsigned int*)(g), \
    (__attribute__((address_space(3))) unsigned int*)(l), 16, 0, 0)

// exact truncation split of fp32 into 3 bf16 (bit patterns) — R0 verified
__device__ inline void split1(float v, unsigned short &a, unsigned short &b,
                              unsigned short &c) {
    unsigned int u = __float_as_uint(v);
    a = (unsigned short)(u >> 16);
    float f1 = __uint_as_float(u & 0xffff0000u);
    float r = v - f1;
    unsigned int ur = __float_as_uint(r);
    b = (unsigned short)(ur >> 16);
    float f2 = __uint_as_float(ur & 0xffff0000u);
    float r2 = r - f2;
    c = (unsigned short)(__float_as_uint(r2) >> 16);
}

// pack 2 consecutive elements into one uint per plane
__device__ inline void split2(float va, float vb, unsigned int &p1,
                              unsigned int &p2, unsigned int &p3) {
    unsigned int ua = __float_as_uint(va), ub = __float_as_uint(vb);
    p1 = (ua >> 16) | (ub & 0xffff0000u);
    float fa = __uint_as_float(ua & 0xffff0000u);
    float fb = __uint_as_float(ub & 0xffff0000u);
    float ra = va - fa, rb = vb - fb;
    unsigned int ura = __float_as_uint(ra), urb = __float_as_uint(rb);
    p2 = (ura >> 16) | (urb & 0xffff0000u);
    float f2a = __uint_as_float(ura & 0xffff0000u);
    float f2b = __uint_as_float(urb & 0xffff0000u);
    float r2a = ra - f2a, r2b = rb - f2b;
    p3 = (__float_as_uint(r2a) >> 16) | (__float_as_uint(r2b) & 0xffff0000u);
}

// Kernel 1 (R11 merged pre-gemm): blocks 0..63 = prep_e (R4-verified body;
// block 0 also zeroes counts+loss, replacing both hipMemsetAsync); blocks
// 64..4159 = transpose_x with fused exact |x|^2 (R4/R6-verified body).
// Branch is block-uniform; prep_e's tiny grid hides under the transpose.
__global__ void prep_all(const float* __restrict__ emb, float* __restrict__ ET,
                         float* __restrict__ sse, unsigned short* __restrict__ eb1,
                         unsigned short* __restrict__ eb2, unsigned short* __restrict__ eb3,
                         const float* __restrict__ x, float* __restrict__ xt,
                         float* __restrict__ ssx, int* __restrict__ counts,
                         float* __restrict__ loss) {
    __shared__ float tile[128][33];
    int tid = threadIdx.x;
    if (blockIdx.x < 64) {
        if (blockIdx.x == 0) {
            ((int4*)counts)[tid] = make_int4(0, 0, 0, 0);   // 1024 ints
            if (tid == 0) loss[0] = 0.f;
        }
        int k   = blockIdx.x * 16 + (tid >> 4);
        int l   = tid & 15;
        float ss = 0.f;
        #pragma unroll
        for (int it = 0; it < 2; ++it) {
            int d0 = l * 4 + it * 64;
            float4 v = *(const float4*)(emb + k * ND + d0);
            ET[(d0+0)*NK + k] = v.x;
            ET[(d0+1)*NK + k] = v.y;
            ET[(d0+2)*NK + k] = v.z;
            ET[(d0+3)*NK + k] = v.w;
            ss = fmaf(v.x, v.x, ss); ss = fmaf(v.y, v.y, ss);
            ss = fmaf(v.z, v.z, ss); ss = fmaf(v.w, v.w, ss);
            int dc  = (l >> 3) + it * 2;
            int d5  = d0 & 31;                 // 0,4,...,28
            int qb  = (d5 >> 3) & 3;           // 16B block index
            int sl  = qb ^ ((k >> 1) & 3);     // swizzled slot (matches LDS read)
            int off = (dc * NK + k) * 32 + (sl << 3) + (d5 & 7);
            ushort4 a, b, c;
            split1(v.x, a.x, b.x, c.x);
            split1(v.y, a.y, b.y, c.y);
            split1(v.z, a.z, b.z, c.z);
            split1(v.w, a.w, b.w, c.w);
            *(ushort4*)(eb1 + off) = a;
            *(ushort4*)(eb2 + off) = b;
            *(ushort4*)(eb3 + off) = c;
        }
        for (int m = 1; m <= 8; m <<= 1) ss += __shfl_xor(ss, m);
        if (l == 0) sse[k] = ss;
    } else {
        int bid = blockIdx.x - 64;
        int b   = bid >> 6;
        int t0  = (bid & 63) << 5;
        int tl  = tid & 31;
        int dg  = tid >> 5;
        const float* xp = x + b * DTSTRIDE + t0 + tl;
        #pragma unroll
        for (int p = 0; p < 16; ++p) {
            int d = p * 8 + dg;
            tile[d][tl] = xp[d * NT];
        }
        __syncthreads();
        float* xtp = xt + (size_t)(b * NT + t0) * ND;
        #pragma unroll
        for (int c = 0; c < 4; ++c) {
            int d = c * 32 + (tid & 31);
            #pragma unroll
            for (int p = 0; p < 4; ++p) {
                int tr = p * 8 + (tid >> 5);
                xtp[tr * ND + d] = tile[d][tr];
            }
        }
        // fused |x|^2: 32 threads, one per t; ascending-d fmaf chain (bit-exact)
        if (tid < 32) {
            float ss = 0.f;
            #pragma unroll 8
            for (int d = 0; d < ND; ++d) {
                float v = tile[d][tid];
                ss = fmaf(v, v, ss);
            }
            ssx[b * NT + t0 + tid] = ss;
        }
    }
}

// stage the (ktp,dcp) e-slice into LDS buffer `bufidx` (async, 6 loads/wave).
__device__ __forceinline__ void stage_eb(int ktp, int dcp, int bufidx, int w, int lane,
        unsigned short* smem, const unsigned short* eb1,
        const unsigned short* eb2, const unsigned short* eb3) {
    int goff = (dcp << 15) + (ktp << 12);   // dc*32768 + kt*4096 ushorts
    int bufo = bufidx * 12288;
    #pragma unroll
    for (int i = 0; i < 2; ++i) {
        int ch = (w << 1) + i;                          // 1KB chunk 0..7
        int so = goff + (ch << 9) + (lane << 3);        // per-lane 16B
        GLL16(eb1 + so, &smem[bufo + 0*4096 + (ch << 9)]);
        GLL16(eb2 + so, &smem[bufo + 1*4096 + (ch << 9)]);
        GLL16(eb3 + so, &smem[bufo + 2*4096 + (ch << 9)]);
    }
}

__device__ __forceinline__ int m3(int v) { return v >= 3 ? v - 3 : v; }

// Kernel 3: MFMA distance GEMM — byte-identical to the R9-PASSING version
// (R8 counted-vmcnt triple-buffer + R9 fused out-tail).
// R10 post-mortem: fusing the A-transpose in regressed (bank conflicts 0->524K,
// double x read, prologue-serial traffic) — reverted to R9.
// Precision note (R1-R3): 6-product bf16 3-plane set is the numerics floor.
// Occupancy notes: (256,2) is the HW truth (R7 spill disaster at (256,3));
// L2-direct B regressed (R5); 16-row waves double LDS traffic (R6).
__launch_bounds__(256, 2)
__global__ void gemm_argmin_mfma(const float* __restrict__ xt,
                                 const unsigned short* __restrict__ eb1,
                                 const unsigned short* __restrict__ eb2,
                                 const unsigned short* __restrict__ eb3,
                                 const float* __restrict__ ssx, const float* __restrict__ sse,
                                 const float* __restrict__ x, const float* __restrict__ ET,
                                 float* __restrict__ out, int* __restrict__ idxi,
                                 int* __restrict__ counts, float* __restrict__ loss) {
    __shared__ unsigned short smem[38912];   // 3 bufs x 12288 + sse 2048 = 76 KB
    int tid = threadIdx.x;
    int b   = blockIdx.x >> 4;
    int t0  = (blockIdx.x & 15) << 7;
    int n0  = b * NT + t0;

    int lane = tid & 63;
    int w    = tid >> 6;          // wave id: rows [w*32, w*32+32)
    int c    = lane & 15;
    int q    = lane >> 4;
    int slot = q ^ ((c >> 1) & 3);

    // prologue: it=0 staging first (overlaps A-split VALU below)
    stage_eb(0, 0, 0, w, lane, smem, eb1, eb2, eb3);

    // sse -> LDS (read in-loop via lgkm, keeping the vmcnt queue staging-pure)
    float* ssef = (float*)&smem[36864];
    ((float4*)ssef)[tid] = ((const float4*)sse)[tid];

    // ---- load + split A fragments once: af[dc][i][plane] (static indexing) ----
    bf16x8 af[4][2][3];
    #pragma unroll
    for (int dc = 0; dc < 4; ++dc) {
        #pragma unroll
        for (int i = 0; i < 2; ++i) {
            const float* xp = xt + (size_t)(n0 + w*32 + i*16 + c) * ND + dc*32 + q*8;
            float4 v0 = *(const float4*)(xp + 0);
            float4 v1 = *(const float4*)(xp + 4);
            unsigned int p1[4], p2[4], p3[4];
            split2(v0.x, v0.y, p1[0], p2[0], p3[0]);
            split2(v0.z, v0.w, p1[1], p2[1], p3[1]);
            split2(v1.x, v1.y, p1[2], p2[2], p3[2]);
            split2(v1.z, v1.w, p1[3], p2[3], p3[3]);
            uint4 u;
            u = make_uint4(p1[0], p1[1], p1[2], p1[3]); af[dc][i][0] = *(bf16x8*)&u;
            u = make_uint4(p2[0], p2[1], p2[2], p2[3]); af[dc][i][1] = *(bf16x8*)&u;
            u = make_uint4(p3[0], p3[1], p3[2], p3[3]); af[dc][i][2] = *(bf16x8*)&u;
        }
    }

    float ssxv[8];
    #pragma unroll
    for (int i = 0; i < 2; ++i)
        #pragma unroll
        for (int rr = 0; rr < 4; ++rr)
            ssxv[i*4+rr] = ssx[n0 + w*32 + i*16 + q*4 + rr];

    // prologue: it=1 staging — must be the LAST VMEM issued before the loop
    stage_eb(0, 1, 1, w, lane, smem, eb1, eb2, eb3);

    float bestD[8]; int bestK[8];
    #pragma unroll
    for (int i = 0; i < 8; ++i) { bestD[i] = 3.4e38f; bestK[i] = 0; }

    floatx4 acc[2][8];
    int b3 = 0;                    // kt % 3

    for (int kt = 0; kt < 8; ++kt) {
        #pragma unroll
        for (int i = 0; i < 2; ++i)
            #pragma unroll
            for (int j = 0; j < 8; ++j)
                acc[i][j] = (floatx4){0.f, 0.f, 0.f, 0.f};

        #pragma unroll
        for (int dc = 0; dc < 4; ++dc) {
            // compute buffer = it % 3, it = kt*4 + dc  (4 == 1 mod 3)
            int cur = (dc == 0 || dc == 3) ? b3 : m3(b3 + dc);

            // barrier(it): vmcnt(6) proves stage(it) landed (newest 6 =
            // stage(it+1)); final iteration drains fully.
            if (kt == 7 && dc == 3) {
                asm volatile("s_waitcnt vmcnt(0) lgkmcnt(0)" ::: "memory");
            } else {
                asm volatile("s_waitcnt vmcnt(6) lgkmcnt(0)" ::: "memory");
            }
            __builtin_amdgcn_s_barrier();

            // issue stage(it+2) into buffer (it+2)%3 — safe: all waves are
            // past the barrier ending compute on that buffer.
            if (dc == 0) {
                stage_eb(kt, 2, m3(b3 + 2), w, lane, smem, eb1, eb2, eb3);
            } else if (dc == 1) {
                stage_eb(kt, 3, b3, w, lane, smem, eb1, eb2, eb3);
            } else if (dc == 2) {
                if (kt < 7) stage_eb(kt + 1, 0, m3(b3 + 1), w, lane, smem, eb1, eb2, eb3);
            } else {
                if (kt < 7) stage_eb(kt + 1, 1, m3(b3 + 2), w, lane, smem, eb1, eb2, eb3);
            }

            int bufo = cur * 12288;
            __builtin_amdgcn_s_setprio(1);
            #pragma unroll
            for (int j = 0; j < 8; ++j) {
                int ro = bufo + ((j << 4) + c) * 32 + slot * 8;
                bf16x8 b1 = *(const bf16x8*)(&smem[ro + 0*4096]);
                bf16x8 b2 = *(const bf16x8*)(&smem[ro + 1*4096]);
                bf16x8 b3f = *(const bf16x8*)(&smem[ro + 2*4096]);
                #pragma unroll
                for (int i = 0; i < 2; ++i) {
                    acc[i][j] = __builtin_amdgcn_mfma_f32_16x16x32_bf16(af[dc][i][0], b1, acc[i][j], 0, 0, 0);
                    acc[i][j] = __builtin_amdgcn_mfma_f32_16x16x32_bf16(af[dc][i][0], b2, acc[i][j], 0, 0, 0);
                    acc[i][j] = __builtin_amdgcn_mfma_f32_16x16x32_bf16(af[dc][i][1], b1, acc[i][j], 0, 0, 0);
                    acc[i][j] = __builtin_amdgcn_mfma_f32_16x16x32_bf16(af[dc][i][1], b2, acc[i][j], 0, 0, 0);
                    acc[i][j] = __builtin_amdgcn_mfma_f32_16x16x32_bf16(af[dc][i][0], b3f, acc[i][j], 0, 0, 0);
                    acc[i][j] = __builtin_amdgcn_mfma_f32_16x16x32_bf16(af[dc][i][2], b1, acc[i][j], 0, 0, 0);
                }
            }
            __builtin_amdgcn_s_setprio(0);
        }

        // epilogue for kt (identical numerics to R0/R4; sse from LDS)
        #pragma unroll
        for (int j = 0; j < 8; ++j) {
            int   kidx = (kt << 7) + (j << 4) + c;
            float se = ssef[(kt << 7) + (j << 4) + c];
            #pragma unroll
            for (int i = 0; i < 2; ++i) {
                #pragma unroll
                for (int rr = 0; rr < 4; ++rr) {
                    float t1   = ssxv[i*4+rr] + se;
                    float dist = fmaf(-2.f, acc[i][j][rr], t1);
                    if (dist < bestD[i*4+rr]) { bestD[i*4+rr] = dist; bestK[i*4+rr] = kidx; }
                }
            }
        }
        b3 = m3(b3 + 1);
    }

    // cross-lane argmin over the 16 c-lanes (ties -> smaller k)
    #pragma unroll
    for (int i = 0; i < 8; ++i) {
        float d = bestD[i]; int kk = bestK[i];
        for (int m = 1; m <= 8; m <<= 1) {
            float od = __shfl_xor(d, m);
            int   ok = __shfl_xor(kk, m);
            if (od < d || (od == d && ok < kk)) { d = od; kk = ok; }
        }
        bestD[i] = d; bestK[i] = kk;
    }
    // per-row k -> LDS buffer 0 (dead after the final barrier)
    int* ksh = (int*)smem;
    if (c == 0) {
        float ls = 0.f;
        #pragma unroll
        for (int i = 0; i < 2; ++i)
            #pragma unroll
            for (int rr = 0; rr < 4; ++rr) {
                int r  = w*32 + i*16 + q*4 + rr;
                int n  = n0 + r;
                int kk = bestK[i*4+rr];
                out[O_IDX + n] = (float)kk;
                idxi[n] = kk;
                ksh[r] = kk;
                atomicAdd(&counts[kk], 1);
                ls += bestD[i*4+rr];
            }
        atomicAdd(loss, ls);
    }
    __syncthreads();

    // ---- fused straight-through output (old out_write, bit-identical) ----
    int tl2 = tid & 127;               // t within tile
    int dh  = tid >> 7;                // 0/1: d parity
    int kk2 = ksh[tl2];
    const float* xp2 = x + b * DTSTRIDE + t0 + tl2;
    float*       op2 = out + O_OUT + b * DTSTRIDE + t0 + tl2;
    #pragma unroll 4
    for (int s = 0; s < 64; ++s) {
        int d = s * 2 + dh;
        float xv = xp2[d * NT];
        float qv = ET[d * NK + kk2];
        op2[d * NT] = xv + (qv - xv);
    }
}

// Kernel 5: exclusive scan of counts + cluster-size/losses (merged, R6 verified).
__global__ void scan_cs(const int* __restrict__ counts, int* __restrict__ offs,
                        int* __restrict__ cur, const float* __restrict__ ch,
                        const float* __restrict__ loss, float* __restrict__ csv,
                        float* __restrict__ out) {
    __shared__ int   s[256];
    __shared__ float red[256];
    int tid = threadIdx.x;
    int c[4]; int sum = 0;
    #pragma unroll
    for (int j = 0; j < 4; ++j) { c[j] = counts[tid*4+j]; sum += c[j]; }
    s[tid] = sum; __syncthreads();
    for (int off = 1; off < 256; off <<= 1) {
        int v = (tid >= off) ? s[tid - off] : 0;
        __syncthreads();
        s[tid] += v;
        __syncthreads();
    }
    int base = (tid == 0) ? 0 : s[tid-1];
    #pragma unroll
    for (int j = 0; j < 4; ++j) {
        offs[tid*4+j] = base; cur[tid*4+j] = base; base += c[j];
    }
    __syncthreads();
    const float DECF = (float)(1.0 - 0.99);
    float sf = 0.f;
    #pragma unroll
    for (int rr = 0; rr < 4; ++rr) {
        int k = tid + rr * 256;
        float cc = (float)counts[k];
        float e = ch[k];
        float hid = e - (e - cc) * DECF;
        sf += hid / DECF;
    }
    red[tid] = sf; __syncthreads();
    for (int off = 128; off > 0; off >>= 1) {
        if (tid < off) red[tid] += red[tid + off];
        __syncthreads();
    }
    float n = red[0];
    const float KEPSF = (float)(1024.0 * 1e-5);
    #pragma unroll
    for (int rr = 0; rr < 4; ++rr) {
        int k = tid + rr * 256;
        float cc = (float)counts[k];
        float e = ch[k];
        float hid = e - (e - cc) * DECF;
        float a = hid / DECF;
        csv[k] = (a + 1e-5f) / (n + KEPSF) * n;
    }
    if (tid == 0) {
        float mean = loss[0] / 16777216.f;
        out[O_LC] = 0.25f * mean;
        out[O_LV] = mean;
    }
}

// Kernel 6: bucket row-ids by k (unchanged).
__global__ void fill_list(const int* __restrict__ idxi, int* __restrict__ cur,
                          int* __restrict__ list) {
    int n = blockIdx.x * 256 + threadIdx.x;
    int k = idxi[n];
    int pos = atomicAdd(&cur[k], 1);
    list[pos] = n;
}

// Kernel 7: dw[k][d] via bucketed gather from xt + fused new_embeddings (R9).
// R11: list segment staged into LDS in coalesced 1024-chunks — removes the
// serial (broadcast list load -> dependent xt gather) latency chain. Each
// thread h still visits m = h, h+2, ... in ascending global order across
// chunk boundaries -> per-thread summation order, and thus dw, bit-identical.
__global__ void dw_sum(const float* __restrict__ xt,
                       const int* __restrict__ counts, const int* __restrict__ offs,
                       const int* __restrict__ list, const float* __restrict__ dwh,
                       const float* __restrict__ csv, float* __restrict__ out) {
    __shared__ float red[128];
    __shared__ int   lbuf[1024];
    int k = blockIdx.x;
    int d = threadIdx.x & 127;
    int h = threadIdx.x >> 7;
    int cnt = counts[k], base = offs[k];
    float acc = 0.f;
    for (int c0 = 0; c0 < cnt; c0 += 1024) {
        int csz = cnt - c0; if (csz > 1024) csz = 1024;
        __syncthreads();                     // lbuf reuse guard
        for (int i = threadIdx.x; i < csz; i += 256) lbuf[i] = list[base + c0 + i];
        __syncthreads();
        for (int m = h; m < csz; m += 2) {
            int n = lbuf[m];
            acc += xt[(size_t)n * ND + d];
        }
    }
    if (h == 1) red[d] = acc;
    __syncthreads();
    if (h == 0) {
        const float DECF = (float)(1.0 - 0.99);
        float dwv = acc + red[d];
        int   kd  = k * ND + d;
        float e   = dwh[kd];
        float hid = e - (e - dwv) * DECF;
        float a   = hid / DECF;
        out[O_NE + kd] = a / csv[k];
    }
}

extern "C" void kernel_launch(void* const* d_in, const int* in_sizes, int n_in,
                              void* d_out, int out_size, void* d_ws, size_t ws_size,
                              hipStream_t stream) {
    const float* x   = (const float*)d_in[0];
    const float* emb = (const float*)d_in[1];
    const float* dwh = (const float*)d_in[2];
    const float* ch  = (const float*)d_in[3];
    float* out = (float*)d_out;
    float* ws  = (float*)d_ws;

    float* ET   = ws + WS_ET;
    float* ssx  = ws + WS_SSX;
    float* sse  = ws + WS_SSE;
    float* csv  = ws + WS_CS;
    int*   counts = (int*)(ws + WS_CNT);
    int*   idxi   = (int*)(ws + WS_IDX);
    float* loss   = ws + WS_LOSS;
    int*   offs   = (int*)(ws + WS_OFFS);
    int*   cur    = (int*)(ws + WS_CUR);
    int*   list   = (int*)(ws + WS_LIST);
    float* xt     = ws + WS_XT;
    unsigned short* eb1 = (unsigned short*)(ws + WS_EB);
    unsigned short* eb2 = eb1 + NK * ND;
    unsigned short* eb3 = eb2 + NK * ND;

    prep_all       <<<4160, 256, 0, stream>>>(emb, ET, sse, eb1, eb2, eb3,
                                              x, xt, ssx, counts, loss);
    gemm_argmin_mfma<<<1024,256, 0, stream>>>(xt, eb1, eb2, eb3, ssx, sse, x, ET,
                                              out, idxi, counts, loss);
    scan_cs        <<<1,    256, 0, stream>>>(counts, offs, cur, ch, loss, csv, out);
    fill_list      <<<512,  256, 0, stream>>>(idxi, cur, list);
    dw_sum         <<<1024, 256, 0, stream>>>(xt, counts, offs, list, dwh, csv, out);
}

// Round 13
// 387.526 us; speedup vs baseline: 1.1189x; 1.0216x over previous
//
#include <hip/hip_runtime.h>

#define NB 64
#define ND 128
#define NT 2048
#define NK 1024
#define NN (NB*NT)            // 131072
#define DTSTRIDE (ND*NT)      // 262144, b-stride in x

typedef __attribute__((ext_vector_type(8))) short bf16x8;
typedef __attribute__((ext_vector_type(4))) float floatx4;

// ---- workspace layout (float index) ----
#define WS_ET    0            // 131072 floats, ET[d][k] fp32 (for out-tail gather)
#define WS_SSX   131072       // 131072 floats, |x_n|^2
#define WS_SSE   262144       // 1024 floats,  |e_k|^2
#define WS_DW    263168       // (unused, kept for layout)
#define WS_CS    394240       // 1024 floats
#define WS_CNT   395264       // 1024 ints, counts
#define WS_IDX   396288       // 131072 ints, argmin indices
#define WS_LOSS  527360       // 1 float
#define WS_OFFS  527364       // 1024 ints
#define WS_CUR   528388       // 1024 ints
#define WS_LIST  529412       // 131072 ints
#define WS_XT    660736       // 16777216 floats, xt[n][d]
#define WS_EB    17437952     // 3 x 131072 ushorts: bf16 e-planes, PRE-SWIZZLED
                              // [dchunk 4][k 1024][slot 4][8] ; slot = q ^ ((k>>1)&3)

// ---- output layout ----
#define O_OUT 0
#define O_LC  16777216
#define O_LV  16777217
#define O_IDX 16777218
#define O_NE  16908290

#define GLL16(g, l) __builtin_amdgcn_global_load_lds( \
    (const __attribute__((address_space(1))) unsigned int*)(g), \
    (__attribute__((address_space(3))) unsigned int*)(l), 16, 0, 0)

// exact truncation split of fp32 into 3 bf16 (bit patterns) — R0 verified
__device__ inline void split1(float v, unsigned short &a, unsigned short &b,
                              unsigned short &c) {
    unsigned int u = __float_as_uint(v);
    a = (unsigned short)(u >> 16);
    float f1 = __uint_as_float(u & 0xffff0000u);
    float r = v - f1;
    unsigned int ur = __float_as_uint(r);
    b = (unsigned short)(ur >> 16);
    float f2 = __uint_as_float(ur & 0xffff0000u);
    float r2 = r - f2;
    c = (unsigned short)(__float_as_uint(r2) >> 16);
}

// pack 2 consecutive elements into one uint per plane
__device__ inline void split2(float va, float vb, unsigned int &p1,
                              unsigned int &p2, unsigned int &p3) {
    unsigned int ua = __float_as_uint(va), ub = __float_as_uint(vb);
    p1 = (ua >> 16) | (ub & 0xffff0000u);
    float fa = __uint_as_float(ua & 0xffff0000u);
    float fb = __uint_as_float(ub & 0xffff0000u);
    float ra = va - fa, rb = vb - fb;
    unsigned int ura = __float_as_uint(ra), urb = __float_as_uint(rb);
    p2 = (ura >> 16) | (urb & 0xffff0000u);
    float f2a = __uint_as_float(ura & 0xffff0000u);
    float f2b = __uint_as_float(urb & 0xffff0000u);
    float r2a = ra - f2a, r2b = rb - f2b;
    p3 = (__float_as_uint(r2a) >> 16) | (__float_as_uint(r2b) & 0xffff0000u);
}

// Kernel 1 (R13): blocks 0..63 = prep_e (R4-verified body; block 0 zeroes
// counts+loss). Blocks 64..1087 = transpose with FLOAT4 global access:
// [128d x 128t] tile per block; reads 512B/wave-d (vs R12's 128B), writes
// 512B/row. LDS [128][129] scalar ops: store phase 4-way, read-out 4-way,
// ssx chain conflict-free. ssx = exact ascending-d fmaf chain (bit-identical,
// tie-critical). xt values are pure copies (bit-identical).
__global__ void prep_all(const float* __restrict__ emb, float* __restrict__ ET,
                         float* __restrict__ sse, unsigned short* __restrict__ eb1,
                         unsigned short* __restrict__ eb2, unsigned short* __restrict__ eb3,
                         const float* __restrict__ x, float* __restrict__ xt,
                         float* __restrict__ ssx, int* __restrict__ counts,
                         float* __restrict__ loss) {
    __shared__ float tile[128][129];   // 64.5 KB
    int tid = threadIdx.x;
    if (blockIdx.x < 64) {
        if (blockIdx.x == 0) {
            ((int4*)counts)[tid] = make_int4(0, 0, 0, 0);   // 1024 ints
            if (tid == 0) loss[0] = 0.f;
        }
        int k   = blockIdx.x * 16 + (tid >> 4);
        int l   = tid & 15;
        float ss = 0.f;
        #pragma unroll
        for (int it = 0; it < 2; ++it) {
            int d0 = l * 4 + it * 64;
            float4 v = *(const float4*)(emb + k * ND + d0);
            ET[(d0+0)*NK + k] = v.x;
            ET[(d0+1)*NK + k] = v.y;
            ET[(d0+2)*NK + k] = v.z;
            ET[(d0+3)*NK + k] = v.w;
            ss = fmaf(v.x, v.x, ss); ss = fmaf(v.y, v.y, ss);
            ss = fmaf(v.z, v.z, ss); ss = fmaf(v.w, v.w, ss);
            int dc  = (l >> 3) + it * 2;
            int d5  = d0 & 31;                 // 0,4,...,28
            int qb  = (d5 >> 3) & 3;           // 16B block index
            int sl  = qb ^ ((k >> 1) & 3);     // swizzled slot (matches LDS read)
            int off = (dc * NK + k) * 32 + (sl << 3) + (d5 & 7);
            ushort4 a, b, c;
            split1(v.x, a.x, b.x, c.x);
            split1(v.y, a.y, b.y, c.y);
            split1(v.z, a.z, b.z, c.z);
            split1(v.w, a.w, b.w, c.w);
            *(ushort4*)(eb1 + off) = a;
            *(ushort4*)(eb2 + off) = b;
            *(ushort4*)(eb3 + off) = c;
        }
        for (int m = 1; m <= 8; m <<= 1) ss += __shfl_xor(ss, m);
        if (l == 0) sse[k] = ss;
    } else {
        int bid = blockIdx.x - 64;
        int b   = bid >> 4;            // 64 batches x 16 t-tiles
        int t0  = (bid & 15) << 7;     // 128-wide t tile
        const float* xb = x + (size_t)b * DTSTRIDE + t0;
        // load phase: float4 global reads (512B per wave-d), scalar LDS stores
        #pragma unroll
        for (int p = 0; p < 16; ++p) {
            int idx = p * 256 + tid;
            int d   = idx >> 5;
            int l4  = (idx & 31) << 2;
            float4 v = *(const float4*)(xb + (size_t)d * NT + l4);
            tile[d][l4+0] = v.x; tile[d][l4+1] = v.y;
            tile[d][l4+2] = v.z; tile[d][l4+3] = v.w;
        }
        __syncthreads();
        // write phase: per row n, gather 4 consecutive d, float4 global write
        float* xtp = xt + (size_t)(b * NT + t0) * ND;
        #pragma unroll
        for (int p = 0; p < 16; ++p) {
            int idx = p * 256 + tid;
            int n   = idx >> 5;
            int j4  = (idx & 31) << 2;
            float4 v;
            v.x = tile[j4+0][n]; v.y = tile[j4+1][n];
            v.z = tile[j4+2][n]; v.w = tile[j4+3][n];
            *(float4*)(xtp + (size_t)n * ND + j4) = v;
        }
        // fused |x|^2: one thread per row; ascending-d fmaf chain (bit-exact)
        if (tid < 128) {
            float ss = 0.f;
            #pragma unroll 8
            for (int d = 0; d < ND; ++d) {
                float v = tile[d][tid];
                ss = fmaf(v, v, ss);
            }
            ssx[b * NT + t0 + tid] = ss;
        }
    }
}

// stage the (ktp,dcp) e-slice into LDS buffer `bufidx` (async, 6 loads/wave).
__device__ __forceinline__ void stage_eb(int ktp, int dcp, int bufidx, int w, int lane,
        unsigned short* smem, const unsigned short* eb1,
        const unsigned short* eb2, const unsigned short* eb3) {
    int goff = (dcp << 15) + (ktp << 12);   // dc*32768 + kt*4096 ushorts
    int bufo = bufidx * 12288;
    #pragma unroll
    for (int i = 0; i < 2; ++i) {
        int ch = (w << 1) + i;                          // 1KB chunk 0..7
        int so = goff + (ch << 9) + (lane << 3);        // per-lane 16B
        GLL16(eb1 + so, &smem[bufo + 0*4096 + (ch << 9)]);
        GLL16(eb2 + so, &smem[bufo + 1*4096 + (ch << 9)]);
        GLL16(eb3 + so, &smem[bufo + 2*4096 + (ch << 9)]);
    }
}

__device__ __forceinline__ int m3(int v) { return v >= 3 ? v - 3 : v; }

// Kernel 3: MFMA distance GEMM — byte-identical to the R9/R12-PASSING version
// (R8 counted-vmcnt triple-buffer + R9 fused out-tail).
// R10 post-mortem: fusing the A-transpose in regressed — reverted.
// Precision note (R1-R3): 6-product bf16 3-plane set is the numerics floor;
// 32x32 MFMA rejected by arithmetic (reorder noise ~5e-7 sits inside the
// proven idx-flip band 1e-7..1.2e-6).
// Occupancy notes: (256,2) is the HW truth (R7 spill disaster at (256,3));
// L2-direct B regressed (R5); 16-row waves double LDS traffic (R6).
__launch_bounds__(256, 2)
__global__ void gemm_argmin_mfma(const float* __restrict__ xt,
                                 const unsigned short* __restrict__ eb1,
                                 const unsigned short* __restrict__ eb2,
                                 const unsigned short* __restrict__ eb3,
                                 const float* __restrict__ ssx, const float* __restrict__ sse,
                                 const float* __restrict__ x, const float* __restrict__ ET,
                                 float* __restrict__ out, int* __restrict__ idxi,
                                 int* __restrict__ counts, float* __restrict__ loss) {
    __shared__ unsigned short smem[38912];   // 3 bufs x 12288 + sse 2048 = 76 KB
    int tid = threadIdx.x;
    int b   = blockIdx.x >> 4;
    int t0  = (blockIdx.x & 15) << 7;
    int n0  = b * NT + t0;

    int lane = tid & 63;
    int w    = tid >> 6;          // wave id: rows [w*32, w*32+32)
    int c    = lane & 15;
    int q    = lane >> 4;
    int slot = q ^ ((c >> 1) & 3);

    // prologue: it=0 staging first (overlaps A-split VALU below)
    stage_eb(0, 0, 0, w, lane, smem, eb1, eb2, eb3);

    // sse -> LDS (read in-loop via lgkm, keeping the vmcnt queue staging-pure)
    float* ssef = (float*)&smem[36864];
    ((float4*)ssef)[tid] = ((const float4*)sse)[tid];

    // ---- load + split A fragments once: af[dc][i][plane] (static indexing) ----
    bf16x8 af[4][2][3];
    #pragma unroll
    for (int dc = 0; dc < 4; ++dc) {
        #pragma unroll
        for (int i = 0; i < 2; ++i) {
            const float* xp = xt + (size_t)(n0 + w*32 + i*16 + c) * ND + dc*32 + q*8;
            float4 v0 = *(const float4*)(xp + 0);
            float4 v1 = *(const float4*)(xp + 4);
            unsigned int p1[4], p2[4], p3[4];
            split2(v0.x, v0.y, p1[0], p2[0], p3[0]);
            split2(v0.z, v0.w, p1[1], p2[1], p3[1]);
            split2(v1.x, v1.y, p1[2], p2[2], p3[2]);
            split2(v1.z, v1.w, p1[3], p2[3], p3[3]);
            uint4 u;
            u = make_uint4(p1[0], p1[1], p1[2], p1[3]); af[dc][i][0] = *(bf16x8*)&u;
            u = make_uint4(p2[0], p2[1], p2[2], p2[3]); af[dc][i][1] = *(bf16x8*)&u;
            u = make_uint4(p3[0], p3[1], p3[2], p3[3]); af[dc][i][2] = *(bf16x8*)&u;
        }
    }

    float ssxv[8];
    #pragma unroll
    for (int i = 0; i < 2; ++i)
        #pragma unroll
        for (int rr = 0; rr < 4; ++rr)
            ssxv[i*4+rr] = ssx[n0 + w*32 + i*16 + q*4 + rr];

    // prologue: it=1 staging — must be the LAST VMEM issued before the loop
    stage_eb(0, 1, 1, w, lane, smem, eb1, eb2, eb3);

    float bestD[8]; int bestK[8];
    #pragma unroll
    for (int i = 0; i < 8; ++i) { bestD[i] = 3.4e38f; bestK[i] = 0; }

    floatx4 acc[2][8];
    int b3 = 0;                    // kt % 3

    for (int kt = 0; kt < 8; ++kt) {
        #pragma unroll
        for (int i = 0; i < 2; ++i)
            #pragma unroll
            for (int j = 0; j < 8; ++j)
                acc[i][j] = (floatx4){0.f, 0.f, 0.f, 0.f};

        #pragma unroll
        for (int dc = 0; dc < 4; ++dc) {
            // compute buffer = it % 3, it = kt*4 + dc  (4 == 1 mod 3)
            int cur = (dc == 0 || dc == 3) ? b3 : m3(b3 + dc);

            // barrier(it): vmcnt(6) proves stage(it) landed (newest 6 =
            // stage(it+1)); final iteration drains fully.
            if (kt == 7 && dc == 3) {
                asm volatile("s_waitcnt vmcnt(0) lgkmcnt(0)" ::: "memory");
            } else {
                asm volatile("s_waitcnt vmcnt(6) lgkmcnt(0)" ::: "memory");
            }
            __builtin_amdgcn_s_barrier();

            // issue stage(it+2) into buffer (it+2)%3 — safe: all waves are
            // past the barrier ending compute on that buffer.
            if (dc == 0) {
                stage_eb(kt, 2, m3(b3 + 2), w, lane, smem, eb1, eb2, eb3);
            } else if (dc == 1) {
                stage_eb(kt, 3, b3, w, lane, smem, eb1, eb2, eb3);
            } else if (dc == 2) {
                if (kt < 7) stage_eb(kt + 1, 0, m3(b3 + 1), w, lane, smem, eb1, eb2, eb3);
            } else {
                if (kt < 7) stage_eb(kt + 1, 1, m3(b3 + 2), w, lane, smem, eb1, eb2, eb3);
            }

            int bufo = cur * 12288;
            __builtin_amdgcn_s_setprio(1);
            #pragma unroll
            for (int j = 0; j < 8; ++j) {
                int ro = bufo + ((j << 4) + c) * 32 + slot * 8;
                bf16x8 b1 = *(const bf16x8*)(&smem[ro + 0*4096]);
                bf16x8 b2 = *(const bf16x8*)(&smem[ro + 1*4096]);
                bf16x8 b3f = *(const bf16x8*)(&smem[ro + 2*4096]);
                #pragma unroll
                for (int i = 0; i < 2; ++i) {
                    acc[i][j] = __builtin_amdgcn_mfma_f32_16x16x32_bf16(af[dc][i][0], b1, acc[i][j], 0, 0, 0);
                    acc[i][j] = __builtin_amdgcn_mfma_f32_16x16x32_bf16(af[dc][i][0], b2, acc[i][j], 0, 0, 0);
                    acc[i][j] = __builtin_amdgcn_mfma_f32_16x16x32_bf16(af[dc][i][1], b1, acc[i][j], 0, 0, 0);
                    acc[i][j] = __builtin_amdgcn_mfma_f32_16x16x32_bf16(af[dc][i][1], b2, acc[i][j], 0, 0, 0);
                    acc[i][j] = __builtin_amdgcn_mfma_f32_16x16x32_bf16(af[dc][i][0], b3f, acc[i][j], 0, 0, 0);
                    acc[i][j] = __builtin_amdgcn_mfma_f32_16x16x32_bf16(af[dc][i][2], b1, acc[i][j], 0, 0, 0);
                }
            }
            __builtin_amdgcn_s_setprio(0);
        }

        // epilogue for kt (identical numerics to R0/R4; sse from LDS)
        #pragma unroll
        for (int j = 0; j < 8; ++j) {
            int   kidx = (kt << 7) + (j << 4) + c;
            float se = ssef[(kt << 7) + (j << 4) + c];
            #pragma unroll
            for (int i = 0; i < 2; ++i) {
                #pragma unroll
                for (int rr = 0; rr < 4; ++rr) {
                    float t1   = ssxv[i*4+rr] + se;
                    float dist = fmaf(-2.f, acc[i][j][rr], t1);
                    if (dist < bestD[i*4+rr]) { bestD[i*4+rr] = dist; bestK[i*4+rr] = kidx; }
                }
            }
        }
        b3 = m3(b3 + 1);
    }

    // cross-lane argmin over the 16 c-lanes (ties -> smaller k)
    #pragma unroll
    for (int i = 0; i < 8; ++i) {
        float d = bestD[i]; int kk = bestK[i];
        for (int m = 1; m <= 8; m <<= 1) {
            float od = __shfl_xor(d, m);
            int   ok = __shfl_xor(kk, m);
            if (od < d || (od == d && ok < kk)) { d = od; kk = ok; }
        }
        bestD[i] = d; bestK[i] = kk;
    }
    // per-row k -> LDS buffer 0 (dead after the final barrier)
    int* ksh = (int*)smem;
    if (c == 0) {
        float ls = 0.f;
        #pragma unroll
        for (int i = 0; i < 2; ++i)
            #pragma unroll
            for (int rr = 0; rr < 4; ++rr) {
                int r  = w*32 + i*16 + q*4 + rr;
                int n  = n0 + r;
                int kk = bestK[i*4+rr];
                out[O_IDX + n] = (float)kk;
                idxi[n] = kk;
                ksh[r] = kk;
                atomicAdd(&counts[kk], 1);
                ls += bestD[i*4+rr];
            }
        atomicAdd(loss, ls);
    }
    __syncthreads();

    // ---- fused straight-through output (old out_write, bit-identical) ----
    int tl2 = tid & 127;               // t within tile
    int dh  = tid >> 7;                // 0/1: d parity
    int kk2 = ksh[tl2];
    const float* xp2 = x + b * DTSTRIDE + t0 + tl2;
    float*       op2 = out + O_OUT + b * DTSTRIDE + t0 + tl2;
    #pragma unroll 4
    for (int s = 0; s < 64; ++s) {
        int d = s * 2 + dh;
        float xv = xp2[d * NT];
        float qv = ET[d * NK + kk2];
        op2[d * NT] = xv + (qv - xv);
    }
}

// Kernel 5: exclusive scan of counts + cluster-size/losses (merged, R6 verified).
__global__ void scan_cs(const int* __restrict__ counts, int* __restrict__ offs,
                        int* __restrict__ cur, const float* __restrict__ ch,
                        const float* __restrict__ loss, float* __restrict__ csv,
                        float* __restrict__ out) {
    __shared__ int   s[256];
    __shared__ float red[256];
    int tid = threadIdx.x;
    int c[4]; int sum = 0;
    #pragma unroll
    for (int j = 0; j < 4; ++j) { c[j] = counts[tid*4+j]; sum += c[j]; }
    s[tid] = sum; __syncthreads();
    for (int off = 1; off < 256; off <<= 1) {
        int v = (tid >= off) ? s[tid - off] : 0;
        __syncthreads();
        s[tid] += v;
        __syncthreads();
    }
    int base = (tid == 0) ? 0 : s[tid-1];
    #pragma unroll
    for (int j = 0; j < 4; ++j) {
        offs[tid*4+j] = base; cur[tid*4+j] = base; base += c[j];
    }
    __syncthreads();
    const float DECF = (float)(1.0 - 0.99);
    float sf = 0.f;
    #pragma unroll
    for (int rr = 0; rr < 4; ++rr) {
        int k = tid + rr * 256;
        float cc = (float)counts[k];
        float e = ch[k];
        float hid = e - (e - cc) * DECF;
        sf += hid / DECF;
    }
    red[tid] = sf; __syncthreads();
    for (int off = 128; off > 0; off >>= 1) {
        if (tid < off) red[tid] += red[tid + off];
        __syncthreads();
    }
    float n = red[0];
    const float KEPSF = (float)(1024.0 * 1e-5);
    #pragma unroll
    for (int rr = 0; rr < 4; ++rr) {
        int k = tid + rr * 256;
        float cc = (float)counts[k];
        float e = ch[k];
        float hid = e - (e - cc) * DECF;
        float a = hid / DECF;
        csv[k] = (a + 1e-5f) / (n + KEPSF) * n;
    }
    if (tid == 0) {
        float mean = loss[0] / 16777216.f;
        out[O_LC] = 0.25f * mean;
        out[O_LV] = mean;
    }
}

// Kernel 6: bucket row-ids by k (unchanged).
__global__ void fill_list(const int* __restrict__ idxi, int* __restrict__ cur,
                          int* __restrict__ list) {
    int n = blockIdx.x * 256 + threadIdx.x;
    int k = idxi[n];
    int pos = atomicAdd(&cur[k], 1);
    list[pos] = n;
}

// Kernel 7: dw[k][d] via bucketed gather from xt + fused new_embeddings (R9),
// with R11/R12-verified LDS list staging.
__global__ void dw_sum(const float* __restrict__ xt,
                       const int* __restrict__ counts, const int* __restrict__ offs,
                       const int* __restrict__ list, const float* __restrict__ dwh,
                       const float* __restrict__ csv, float* __restrict__ out) {
    __shared__ float red[128];
    __shared__ int   lbuf[1024];
    int k = blockIdx.x;
    int d = threadIdx.x & 127;
    int h = threadIdx.x >> 7;
    int cnt = counts[k], base = offs[k];
    float acc = 0.f;
    for (int c0 = 0; c0 < cnt; c0 += 1024) {
        int csz = cnt - c0; if (csz > 1024) csz = 1024;
        __syncthreads();                     // lbuf reuse guard
        for (int i = threadIdx.x; i < csz; i += 256) lbuf[i] = list[base + c0 + i];
        __syncthreads();
        for (int m = h; m < csz; m += 2) {
            int n = lbuf[m];
            acc += xt[(size_t)n * ND + d];
        }
    }
    if (h == 1) red[d] = acc;
    __syncthreads();
    if (h == 0) {
        const float DECF = (float)(1.0 - 0.99);
        float dwv = acc + red[d];
        int   kd  = k * ND + d;
        float e   = dwh[kd];
        float hid = e - (e - dwv) * DECF;
        float a   = hid / DECF;
        out[O_NE + kd] = a / csv[k];
    }
}

extern "C" void kernel_launch(void* const* d_in, const int* in_sizes, int n_in,
                              void* d_out, int out_size, void* d_ws, size_t ws_size,
                              hipStream_t stream) {
    const float* x   = (const float*)d_in[0];
    const float* emb = (const float*)d_in[1];
    const float* dwh = (const float*)d_in[2];
    const float* ch  = (const float*)d_in[3];
    float* out = (float*)d_out;
    float* ws  = (float*)d_ws;

    float* ET   = ws + WS_ET;
    float* ssx  = ws + WS_SSX;
    float* sse  = ws + WS_SSE;
    float* csv  = ws + WS_CS;
    int*   counts = (int*)(ws + WS_CNT);
    int*   idxi   = (int*)(ws + WS_IDX);
    float* loss   = ws + WS_LOSS;
    int*   offs   = (int*)(ws + WS_OFFS);
    int*   cur    = (int*)(ws + WS_CUR);
    int*   list   = (int*)(ws + WS_LIST);
    float* xt     = ws + WS_XT;
    unsigned short* eb1 = (unsigned short*)(ws + WS_EB);
    unsigned short* eb2 = eb1 + NK * ND;
    unsigned short* eb3 = eb2 + NK * ND;

    prep_all       <<<1088, 256, 0, stream>>>(emb, ET, sse, eb1, eb2, eb3,
                                              x, xt, ssx, counts, loss);
    gemm_argmin_mfma<<<1024,256, 0, stream>>>(xt, eb1, eb2, eb3, ssx, sse, x, ET,
                                              out, idxi, counts, loss);
    scan_cs        <<<1,    256, 0, stream>>>(counts, offs, cur, ch, loss, csv, out);
    fill_list      <<<512,  256, 0, stream>>>(idxi, cur, list);
    dw_sum         <<<1024, 256, 0, stream>>>(xt, counts, offs, list, dwh, csv, out);
}